// Round 1
// baseline (471.860 us; speedup 1.0000x reference)
//
#include <hip/hip_runtime.h>
#include <hip/hip_bf16.h>

#define B_   8
#define N_   16384
#define C_   64
#define M_   256
#define NPB  1048576   // N_*C_ per batch

// ---------------------------------------------------------------------------
// Conv as split-K GEMM.  out[b,m=(oh,ow),co] = sum_{kh,kw,ci} x[b, n, csrc]*K[e,co]
// with csrc = (oh*8+kh)>>1, n = ((oh*8+kh)&1)*8192 + (ow*8+kw)*64 + ci,
// e = (kh*8+kw)*64+ci.  grid = 32 m-tiles * 8 kh ; block 256 ; 64x64 tile.
// ---------------------------------------------------------------------------
__global__ __launch_bounds__(256) void conv_gemm(const float* __restrict__ x,
                                                 const float* __restrict__ Kw,
                                                 float* __restrict__ xr_part) {
  const int kh = blockIdx.x & 7;
  const int mt = blockIdx.x >> 3;     // 0..31
  const int b  = mt >> 2;
  const int tb = mt & 3;              // 64-row tile within batch
  const int t  = threadIdx.x;
  const int tc = t & 15;              // 4 co per thread
  const int tm = t >> 4;              // 4 m per thread

  __shared__ float As[64][68];        // [ci][m]  (transposed A tile)
  __shared__ float Ks[64][68];        // [ci][co]

  float acc[4][4] = {{0.f}};

  // A-staging role: this thread loads rows of m = a_m, ci = a_q*16 .. +16
  const int a_m = t & 63;
  const int a_q = t >> 6;
  const int oh  = (tb * 64 + a_m) >> 4;
  const int ow  = a_m & 15;
  const int h   = oh * 8 + kh;
  const int csrc = h >> 1;
  const int par  = h & 1;
  const size_t xb = (size_t)b * NPB + csrc;

  for (int kw = 0; kw < 8; ++kw) {
    __syncthreads();
    // ---- stage A (gather, LDS-transposed) ----
    const int n0 = par * 8192 + (ow * 8 + kw) * 64 + a_q * 16;
    #pragma unroll
    for (int i = 0; i < 16; ++i)
      As[a_q * 16 + i][a_m] = x[xb + (size_t)(n0 + i) * 64];
    // ---- stage K chunk (contiguous) ----
    const int ebase = (kh * 8 + kw) * 64;
    for (int idx = t; idx < 4096; idx += 256)
      Ks[idx >> 6][idx & 63] = Kw[(size_t)(ebase + (idx >> 6)) * 64 + (idx & 63)];
    __syncthreads();
    // ---- 64x64x64 compute, 4x4 per thread ----
    #pragma unroll 4
    for (int ee = 0; ee < 64; ++ee) {
      const float4 a4 = *(const float4*)&As[ee][tm * 4];
      const float4 b4 = *(const float4*)&Ks[ee][tc * 4];
      acc[0][0] += a4.x * b4.x; acc[0][1] += a4.x * b4.y; acc[0][2] += a4.x * b4.z; acc[0][3] += a4.x * b4.w;
      acc[1][0] += a4.y * b4.x; acc[1][1] += a4.y * b4.y; acc[1][2] += a4.y * b4.z; acc[1][3] += a4.y * b4.w;
      acc[2][0] += a4.z * b4.x; acc[2][1] += a4.z * b4.y; acc[2][2] += a4.z * b4.z; acc[2][3] += a4.z * b4.w;
      acc[3][0] += a4.w * b4.x; acc[3][1] += a4.w * b4.y; acc[3][2] += a4.w * b4.z; acc[3][3] += a4.w * b4.w;
    }
  }
  // ---- write partial: xr_part[kh][(b*256 + m)*64 + co] ----
  float* dst = xr_part + (size_t)kh * (M_ * B_ * 64)
             + ((size_t)(b * M_ + tb * 64 + tm * 4)) * 64 + tc * 4;
  #pragma unroll
  for (int i = 0; i < 4; ++i) {
    float4 v = make_float4(acc[i][0], acc[i][1], acc[i][2], acc[i][3]);
    *(float4*)(dst + (size_t)i * 64) = v;
  }
}

// ---------------------------------------------------------------------------
// Reduce split-K partials + bias, LayerNorm (eps inside rsqrt), then kv GEMV.
// One 64-thread wave per reduced row (2048 rows).
// ---------------------------------------------------------------------------
__global__ __launch_bounds__(64) void ln_kv(const float* __restrict__ xr_part,
                                            const float* __restrict__ sr_bias,
                                            const float* __restrict__ gamma,
                                            const float* __restrict__ beta,
                                            const float* __restrict__ Wkv,
                                            float* __restrict__ kbuf,
                                            float* __restrict__ vbuf) {
  const int row = blockIdx.x;   // 0..2047  (= b*256 + m)
  const int c   = threadIdx.x;  // 0..63
  float val = sr_bias[c];
  #pragma unroll
  for (int s = 0; s < 8; ++s)
    val += xr_part[(size_t)s * (M_ * B_ * 64) + (size_t)row * 64 + c];

  float sum = val;
  #pragma unroll
  for (int off = 32; off; off >>= 1) sum += __shfl_xor(sum, off, 64);
  const float mu = sum * (1.f / 64.f);
  const float d  = val - mu;
  float vs = d * d;
  #pragma unroll
  for (int off = 32; off; off >>= 1) vs += __shfl_xor(vs, off, 64);
  const float rs = rsqrtf(vs * (1.f / 64.f) + 1e-3f);
  const float ln = d * rs * gamma[c] + beta[c];

  __shared__ float lnrow[64];
  lnrow[c] = ln;
  __syncthreads();

  float ka = 0.f, va = 0.f;
  #pragma unroll 8
  for (int cc = 0; cc < 64; ++cc) {
    const float l = lnrow[cc];
    ka += l * Wkv[cc * 128 + c];
    va += l * Wkv[cc * 128 + 64 + c];
  }
  kbuf[(size_t)row * 64 + c] = ka;
  vbuf[(size_t)row * 64 + c] = va;
}

// ---------------------------------------------------------------------------
// Fused q-GEMM + attention (softmax over M=256, no max-subtract: |score|<~1)
// + output projection.  One thread per query row; 512 blocks x 256 threads.
// LDS (64 KB): phase A: Wq[0,4096) ; phase B: k[0,8192) v[8192,16384) ;
// phase C: per-thread spill column [c*256 + t] (own data only).
// ---------------------------------------------------------------------------
__global__ __launch_bounds__(256) void attn_fused(const float* __restrict__ x,
                                                  const float* __restrict__ Wq,
                                                  const float* __restrict__ kbuf,
                                                  const float* __restrict__ vbuf,
                                                  const float* __restrict__ Wp,
                                                  const float* __restrict__ bp,
                                                  float* __restrict__ out) {
  __shared__ float lds[16384];
  const int t    = threadIdx.x;
  const int b    = blockIdx.x >> 6;
  const int tile = blockIdx.x & 63;
  const size_t rowbase = (size_t)b * N_ + (size_t)tile * 256 + t;

  // ---------------- phase A: q = x_row @ Wq ----------------
  {
    const float4* wsrc = (const float4*)Wq;
    float4* wdst = (float4*)lds;
    for (int i = t; i < 1024; i += 256) wdst[i] = wsrc[i];
  }
  __syncthreads();

  float q[64];
  #pragma unroll
  for (int j = 0; j < 64; ++j) q[j] = 0.f;
  {
    const float4* xsrc = (const float4*)(x + rowbase * 64);
    for (int c4 = 0; c4 < 16; ++c4) {
      const float4 xv = xsrc[c4];
      #pragma unroll
      for (int cc = 0; cc < 4; ++cc) {
        const float xc = (cc == 0) ? xv.x : (cc == 1) ? xv.y : (cc == 2) ? xv.z : xv.w;
        const float4* wrow = (const float4*)&lds[(c4 * 4 + cc) * 64];
        #pragma unroll
        for (int j4 = 0; j4 < 16; ++j4) {
          const float4 w = wrow[j4];
          q[j4 * 4 + 0] += xc * w.x; q[j4 * 4 + 1] += xc * w.y;
          q[j4 * 4 + 2] += xc * w.z; q[j4 * 4 + 3] += xc * w.w;
        }
      }
    }
  }

  // ---------------- phase B: online attention over 2 chunks of 128 ----------
  float oa[64];
  #pragma unroll
  for (int j = 0; j < 64; ++j) oa[j] = 0.f;
  float ss = 0.f;

  for (int ch = 0; ch < 2; ++ch) {
    __syncthreads();
    {
      const float4* ks = (const float4*)(kbuf + ((size_t)b * M_ + ch * 128) * 64);
      const float4* vs = (const float4*)(vbuf + ((size_t)b * M_ + ch * 128) * 64);
      float4* kd = (float4*)lds;
      float4* vd = (float4*)(lds + 8192);
      for (int i = t; i < 2048; i += 256) { kd[i] = ks[i]; vd[i] = vs[i]; }
    }
    __syncthreads();
    #pragma unroll 2
    for (int m = 0; m < 128; ++m) {
      const float4* krow = (const float4*)&lds[m * 64];
      float s0 = 0.f, s1 = 0.f, s2 = 0.f, s3 = 0.f;
      #pragma unroll
      for (int c4 = 0; c4 < 16; ++c4) {
        const float4 kk = krow[c4];
        s0 += q[c4 * 4 + 0] * kk.x; s1 += q[c4 * 4 + 1] * kk.y;
        s2 += q[c4 * 4 + 2] * kk.z; s3 += q[c4 * 4 + 3] * kk.w;
      }
      const float sc = (s0 + s1) + (s2 + s3);
      const float p = __expf(sc * 0.125f);
      ss += p;
      const float4* vrow = (const float4*)&lds[8192 + m * 64];
      #pragma unroll
      for (int j4 = 0; j4 < 16; ++j4) {
        const float4 vv = vrow[j4];
        oa[j4 * 4 + 0] += p * vv.x; oa[j4 * 4 + 1] += p * vv.y;
        oa[j4 * 4 + 2] += p * vv.z; oa[j4 * 4 + 3] += p * vv.w;
      }
    }
  }

  // ---------------- phase C: proj (spill own oa column to LDS so the
  // contraction loop can use a runtime index without register scratch) -------
  __syncthreads();            // everyone done reading k/v chunks
  const float inv = 1.0f / ss;
  #pragma unroll
  for (int c = 0; c < 64; ++c) lds[c * 256 + t] = oa[c] * inv;
  // (no barrier needed: each thread reads only its own column)

  float res[64];
  {
    const float4* bp4 = (const float4*)bp;
    #pragma unroll
    for (int j4 = 0; j4 < 16; ++j4) {
      const float4 bb = bp4[j4];
      res[j4 * 4 + 0] = bb.x; res[j4 * 4 + 1] = bb.y;
      res[j4 * 4 + 2] = bb.z; res[j4 * 4 + 3] = bb.w;
    }
  }
  #pragma unroll 4
  for (int c = 0; c < 64; ++c) {
    const float oc = lds[c * 256 + t];
    const float4* wrow = (const float4*)(Wp + c * 64);
    #pragma unroll
    for (int j4 = 0; j4 < 16; ++j4) {
      const float4 w = wrow[j4];
      res[j4 * 4 + 0] += oc * w.x; res[j4 * 4 + 1] += oc * w.y;
      res[j4 * 4 + 2] += oc * w.z; res[j4 * 4 + 3] += oc * w.w;
    }
  }
  float4* od = (float4*)(out + rowbase * 64);
  #pragma unroll
  for (int j4 = 0; j4 < 16; ++j4)
    od[j4] = make_float4(res[j4 * 4 + 0], res[j4 * 4 + 1], res[j4 * 4 + 2], res[j4 * 4 + 3]);
}

// ---------------------------------------------------------------------------
extern "C" void kernel_launch(void* const* d_in, const int* in_sizes, int n_in,
                              void* d_out, int out_size, void* d_ws, size_t ws_size,
                              hipStream_t stream) {
  const float* x   = (const float*)d_in[0];
  // d_in[1], d_in[2] are H, W scalars (128, 128) — shapes hardcoded
  const float* Wq  = (const float*)d_in[3];
  const float* Wkv = (const float*)d_in[4];
  const float* Kw  = (const float*)d_in[5];   // sr_kernel [8,8,64,64]
  const float* sb  = (const float*)d_in[6];
  const float* gam = (const float*)d_in[7];
  const float* bet = (const float*)d_in[8];
  const float* Wp  = (const float*)d_in[9];
  const float* bp  = (const float*)d_in[10];
  float* out = (float*)d_out;

  float* ws = (float*)d_ws;
  float* xr_part = ws;                        // 8 * 2048 * 64   = 1,048,576 f
  float* kbuf    = ws + 1048576;              // 2048 * 64       = 131,072 f
  float* vbuf    = kbuf + 131072;             // 2048 * 64       = 131,072 f

  conv_gemm<<<256, 256, 0, stream>>>(x, Kw, xr_part);
  ln_kv<<<2048, 64, 0, stream>>>(xr_part, sb, gam, bet, Wkv, kbuf, vbuf);
  attn_fused<<<512, 256, 0, stream>>>(x, Wq, kbuf, vbuf, Wp, bp, out);
}

// Round 2
// 101.209 us; speedup vs baseline: 4.6622x; 4.6622x over previous
//
#include <hip/hip_runtime.h>
#include <hip/hip_bf16.h>

#define B_   8
#define N_   16384
#define C_   64
#define M_   256
#define NPB  1048576   // N_*C_ per batch

typedef __attribute__((ext_vector_type(8))) short short8v;   // 8 bf16 = 4 VGPR
typedef __attribute__((ext_vector_type(16))) float f32x16;   // MFMA 32x32 acc

union FragU { short8v s8; unsigned u[4]; };

__device__ inline unsigned pkbf(float a, float b) {
  union { __hip_bfloat162 h2; unsigned u; } cv;
  cv.h2 = __float22bfloat162_rn(make_float2(a, b));
  return cv.u;
}
__device__ inline unsigned short bfbits(float a) {
  union { __hip_bfloat16 h; unsigned short u; } cv;
  cv.h = __float2bfloat16(a);
  return cv.u;
}
__device__ inline short8v ld8(const unsigned short* p) {
  return *(const short8v*)p;
}

// Repack a 32x32 MFMA D-tile (rows r: (reg&3)+8*(reg>>2)+4*hi ; col q=lane&31)
// into two B-operand fragments (frag t: element j holds row 16t+8*hi+j, col q).
// Cross-half exchange via shfl_xor(32) + select (layout-safe version).
__device__ inline void repack16(const f32x16 s, const int hi, FragU& f0, FragU& f1) {
  #pragma unroll
  for (int h = 0; h < 2; ++h) {
    FragU& f = h ? f1 : f0;
    unsigned a0 = pkbf(s[8*h+0], s[8*h+1]);   // rows {0,1}+4hi  (+16h)
    unsigned a1 = pkbf(s[8*h+2], s[8*h+3]);   // rows {2,3}+4hi
    unsigned a2 = pkbf(s[8*h+4], s[8*h+5]);   // rows {8,9}+4hi
    unsigned a3 = pkbf(s[8*h+6], s[8*h+7]);   // rows {10,11}+4hi
    unsigned b0 = (unsigned)__shfl_xor((int)a0, 32);
    unsigned b1 = (unsigned)__shfl_xor((int)a1, 32);
    unsigned b2 = (unsigned)__shfl_xor((int)a2, 32);
    unsigned b3 = (unsigned)__shfl_xor((int)a3, 32);
    f.u[0] = hi ? b2 : a0;   // rows 8hi+{0,1}
    f.u[1] = hi ? b3 : a1;   // rows 8hi+{2,3}
    f.u[2] = hi ? a2 : b0;   // rows 8hi+{4,5}
    f.u[3] = hi ? a3 : b1;   // rows 8hi+{6,7}
  }
}

// ---------------------------------------------------------------------------
// Conv as split-K GEMM (fp32, unchanged from R1 — ~8 us, accuracy anchor).
// ---------------------------------------------------------------------------
__global__ __launch_bounds__(256) void conv_gemm(const float* __restrict__ x,
                                                 const float* __restrict__ Kw,
                                                 float* __restrict__ xr_part) {
  const int kh = blockIdx.x & 7;
  const int mt = blockIdx.x >> 3;
  const int b  = mt >> 2;
  const int tb = mt & 3;
  const int t  = threadIdx.x;
  const int tc = t & 15;
  const int tm = t >> 4;

  __shared__ float As[64][68];
  __shared__ float Ks[64][68];

  float acc[4][4] = {{0.f}};

  const int a_m = t & 63;
  const int a_q = t >> 6;
  const int oh  = (tb * 64 + a_m) >> 4;
  const int ow  = a_m & 15;
  const int h   = oh * 8 + kh;
  const int csrc = h >> 1;
  const int par  = h & 1;
  const size_t xb = (size_t)b * NPB + csrc;

  for (int kw = 0; kw < 8; ++kw) {
    __syncthreads();
    const int n0 = par * 8192 + (ow * 8 + kw) * 64 + a_q * 16;
    #pragma unroll
    for (int i = 0; i < 16; ++i)
      As[a_q * 16 + i][a_m] = x[xb + (size_t)(n0 + i) * 64];
    const int ebase = (kh * 8 + kw) * 64;
    for (int idx = t; idx < 4096; idx += 256)
      Ks[idx >> 6][idx & 63] = Kw[(size_t)(ebase + (idx >> 6)) * 64 + (idx & 63)];
    __syncthreads();
    #pragma unroll 4
    for (int ee = 0; ee < 64; ++ee) {
      const float4 a4 = *(const float4*)&As[ee][tm * 4];
      const float4 b4 = *(const float4*)&Ks[ee][tc * 4];
      acc[0][0] += a4.x * b4.x; acc[0][1] += a4.x * b4.y; acc[0][2] += a4.x * b4.z; acc[0][3] += a4.x * b4.w;
      acc[1][0] += a4.y * b4.x; acc[1][1] += a4.y * b4.y; acc[1][2] += a4.y * b4.z; acc[1][3] += a4.y * b4.w;
      acc[2][0] += a4.z * b4.x; acc[2][1] += a4.z * b4.y; acc[2][2] += a4.z * b4.z; acc[2][3] += a4.z * b4.w;
      acc[3][0] += a4.w * b4.x; acc[3][1] += a4.w * b4.y; acc[3][2] += a4.w * b4.z; acc[3][3] += a4.w * b4.w;
    }
  }
  float* dst = xr_part + (size_t)kh * (M_ * B_ * 64)
             + ((size_t)(b * M_ + tb * 64 + tm * 4)) * 64 + tc * 4;
  #pragma unroll
  for (int i = 0; i < 4; ++i) {
    float4 v = make_float4(acc[i][0], acc[i][1], acc[i][2], acc[i][3]);
    *(float4*)(dst + (size_t)i * 64) = v;
  }
}

// ---------------------------------------------------------------------------
// Reduce split-K + bias, LayerNorm, kv GEMV (fp32), emit bf16 K and bf16 V^T.
// ---------------------------------------------------------------------------
__global__ __launch_bounds__(64) void ln_kv(const float* __restrict__ xr_part,
                                            const float* __restrict__ sr_bias,
                                            const float* __restrict__ gamma,
                                            const float* __restrict__ beta,
                                            const float* __restrict__ Wkv,
                                            unsigned short* __restrict__ kb16,
                                            unsigned short* __restrict__ vt16) {
  const int row = blockIdx.x;   // 0..2047  (= b*256 + m)
  const int c   = threadIdx.x;  // 0..63
  float val = sr_bias[c];
  #pragma unroll
  for (int s = 0; s < 8; ++s)
    val += xr_part[(size_t)s * (M_ * B_ * 64) + (size_t)row * 64 + c];

  float sum = val;
  #pragma unroll
  for (int off = 32; off; off >>= 1) sum += __shfl_xor(sum, off, 64);
  const float mu = sum * (1.f / 64.f);
  const float d  = val - mu;
  float vs = d * d;
  #pragma unroll
  for (int off = 32; off; off >>= 1) vs += __shfl_xor(vs, off, 64);
  const float rs = rsqrtf(vs * (1.f / 64.f) + 1e-3f);
  const float ln = d * rs * gamma[c] + beta[c];

  __shared__ float lnrow[64];
  lnrow[c] = ln;
  __syncthreads();

  float ka = 0.f, va = 0.f;
  #pragma unroll 8
  for (int cc = 0; cc < 64; ++cc) {
    const float l = lnrow[cc];
    ka += l * Wkv[cc * 128 + c];
    va += l * Wkv[cc * 128 + 64 + c];
  }
  kb16[(size_t)row * 64 + c] = bfbits(ka);
  const int bb = row >> 8, m = row & 255;
  vt16[(bb << 14) + (c << 8) + m] = bfbits(va);   // V^T [b][d][m]
}

// ---------------------------------------------------------------------------
// Tiny prep: Wq^T and Wp^T in bf16.
// ---------------------------------------------------------------------------
__global__ void prep_w(const float* __restrict__ Wq, const float* __restrict__ Wp,
                       unsigned short* __restrict__ wqt, unsigned short* __restrict__ wpt) {
  const int i = blockIdx.x * 256 + threadIdx.x;
  if (i < 4096) {
    const int co = i >> 6, ci = i & 63;
    wqt[i] = bfbits(Wq[ci * 64 + co]);
    wpt[i] = bfbits(Wp[ci * 64 + co]);
  }
}

// ---------------------------------------------------------------------------
// Fused MFMA attention: Q^T = Wq^T X^T ; S^T = K Q^T ; P=exp(S*scale);
// O^T = V^T P^T ; F^T = Wp^T O^T + bp.  One wave = 32 query rows; 4 waves/block.
// All stages swapped (queries = D columns); repack16 bridges D -> B-operand.
// ---------------------------------------------------------------------------
__global__ __launch_bounds__(256) void attn_mfma(const float* __restrict__ x,
                                                 const unsigned short* __restrict__ kb16,
                                                 const unsigned short* __restrict__ vt16,
                                                 const unsigned short* __restrict__ wqt,
                                                 const unsigned short* __restrict__ wpt,
                                                 const float* __restrict__ bp,
                                                 float* __restrict__ out) {
  __shared__ float lds[128 * 68];
  const int t    = threadIdx.x;
  const int w    = t >> 6;
  const int lane = t & 63;
  const int l31  = lane & 31;
  const int hi   = lane >> 5;
  const int b    = blockIdx.x >> 7;
  const int tile = blockIdx.x & 127;
  const size_t nrow = (size_t)b * N_ + (size_t)tile * 128;
  const int qrow = w * 32 + l31;

  // ---- X^T B-fragments: own query row, fp32 -> bf16 ----
  const float* xrow = x + (nrow + qrow) * 64;
  FragU xb[4];
  #pragma unroll
  for (int tt = 0; tt < 4; ++tt) {
    const float* p = xrow + 16 * tt + 8 * hi;
    const float4 x0 = *(const float4*)(p);
    const float4 x1 = *(const float4*)(p + 4);
    xb[tt].u[0] = pkbf(x0.x, x0.y); xb[tt].u[1] = pkbf(x0.z, x0.w);
    xb[tt].u[2] = pkbf(x1.x, x1.y); xb[tt].u[3] = pkbf(x1.z, x1.w);
  }

  // ---- Q^T = Wq^T · X^T  (2 c_out tiles) -> repack to B-frags ----
  FragU Qb[4];
  #pragma unroll
  for (int ct = 0; ct < 2; ++ct) {
    f32x16 qa;
    #pragma unroll
    for (int r = 0; r < 16; ++r) qa[r] = 0.f;
    #pragma unroll
    for (int tt = 0; tt < 4; ++tt) {
      const short8v aw = ld8(wqt + (l31 + 32 * ct) * 64 + 16 * tt + 8 * hi);
      qa = __builtin_amdgcn_mfma_f32_32x32x16_bf16(aw, xb[tt].s8, qa, 0, 0, 0);
    }
    repack16(qa, hi, Qb[2 * ct], Qb[2 * ct + 1]);
  }

  // ---- main attention loop over 8 key tiles of 32 ----
  const unsigned short* kbb = kb16 + b * 16384 + l31 * 64 + 8 * hi;
  const unsigned short* vbb = vt16 + b * 16384 + l31 * 256 + 8 * hi;
  f32x16 O0, O1;
  #pragma unroll
  for (int r = 0; r < 16; ++r) { O0[r] = 0.f; O1[r] = 0.f; }
  float ss = 0.f;

  #pragma unroll 2
  for (int kt = 0; kt < 8; ++kt) {
    f32x16 S;
    #pragma unroll
    for (int r = 0; r < 16; ++r) S[r] = 0.f;
    #pragma unroll
    for (int tt = 0; tt < 4; ++tt) {
      const short8v ak = ld8(kbb + kt * 2048 + 16 * tt);
      S = __builtin_amdgcn_mfma_f32_32x32x16_bf16(ak, Qb[tt].s8, S, 0, 0, 0);
    }
    f32x16 P;
    #pragma unroll
    for (int r = 0; r < 16; ++r) {
      const float pv = __expf(S[r] * 0.125f);   // scale = hd^-0.5 = 1/8
      P[r] = pv; ss += pv;
    }
    FragU f0, f1;
    repack16(P, hi, f0, f1);
    const short8v v00 = ld8(vbb + (2 * kt) * 16);
    const short8v v01 = ld8(vbb + (2 * kt + 1) * 16);
    const short8v v10 = ld8(vbb + 32 * 256 + (2 * kt) * 16);
    const short8v v11 = ld8(vbb + 32 * 256 + (2 * kt + 1) * 16);
    O0 = __builtin_amdgcn_mfma_f32_32x32x16_bf16(v00, f0.s8, O0, 0, 0, 0);
    O0 = __builtin_amdgcn_mfma_f32_32x32x16_bf16(v01, f1.s8, O0, 0, 0, 0);
    O1 = __builtin_amdgcn_mfma_f32_32x32x16_bf16(v10, f0.s8, O1, 0, 0, 0);
    O1 = __builtin_amdgcn_mfma_f32_32x32x16_bf16(v11, f1.s8, O1, 0, 0, 0);
  }

  // ---- normalize, repack O^T, project ----
  ss += __shfl_xor(ss, 32);          // own half + partner half = full row sum
  const float inv = 1.f / ss;
  #pragma unroll
  for (int r = 0; r < 16; ++r) { O0[r] *= inv; O1[r] *= inv; }
  FragU Ob[4];
  repack16(O0, hi, Ob[0], Ob[1]);
  repack16(O1, hi, Ob[2], Ob[3]);

  #pragma unroll
  for (int ct = 0; ct < 2; ++ct) {
    f32x16 F;
    #pragma unroll
    for (int r = 0; r < 16; ++r) F[r] = 0.f;
    #pragma unroll
    for (int tt = 0; tt < 4; ++tt) {
      const short8v aw = ld8(wpt + (l31 + 32 * ct) * 64 + 16 * tt + 8 * hi);
      F = __builtin_amdgcn_mfma_f32_32x32x16_bf16(aw, Ob[tt].s8, F, 0, 0, 0);
    }
    #pragma unroll
    for (int g = 0; g < 4; ++g) {
      const int co = 32 * ct + 8 * g + 4 * hi;
      const float4 bb = *(const float4*)(bp + co);
      *(float4*)&lds[qrow * 68 + co] =
          make_float4(F[4 * g + 0] + bb.x, F[4 * g + 1] + bb.y,
                      F[4 * g + 2] + bb.z, F[4 * g + 3] + bb.w);
    }
  }

  // ---- coalesced store via LDS transpose ----
  __syncthreads();
  float4* out4 = (float4*)(out + nrow * 64);
  #pragma unroll
  for (int i = 0; i < 8; ++i) {
    const int idx = i * 256 + t;
    const int row = idx >> 4, c4 = idx & 15;
    out4[idx] = *(const float4*)&lds[row * 68 + c4 * 4];
  }
}

// ---------------------------------------------------------------------------
extern "C" void kernel_launch(void* const* d_in, const int* in_sizes, int n_in,
                              void* d_out, int out_size, void* d_ws, size_t ws_size,
                              hipStream_t stream) {
  const float* x   = (const float*)d_in[0];
  const float* Wq  = (const float*)d_in[3];
  const float* Wkv = (const float*)d_in[4];
  const float* Kw  = (const float*)d_in[5];
  const float* sb  = (const float*)d_in[6];
  const float* gam = (const float*)d_in[7];
  const float* bet = (const float*)d_in[8];
  const float* Wp  = (const float*)d_in[9];
  const float* bp  = (const float*)d_in[10];
  float* out = (float*)d_out;

  float* xr_part = (float*)d_ws;                                  // 4,194,304 B
  unsigned short* kb16 = (unsigned short*)((char*)d_ws + 4194304); // 256 KB
  unsigned short* vt16 = kb16 + 131072;                            // 256 KB
  unsigned short* wqt  = vt16 + 131072;                            // 8 KB
  unsigned short* wpt  = wqt + 4096;                               // 8 KB

  prep_w<<<16, 256, 0, stream>>>(Wq, Wp, wqt, wpt);
  conv_gemm<<<256, 256, 0, stream>>>(x, Kw, xr_part);
  ln_kv<<<2048, 64, 0, stream>>>(xr_part, sb, gam, bet, Wkv, kb16, vt16);
  attn_mfma<<<1024, 256, 0, stream>>>(x, kb16, vt16, wqt, wpt, bp, out);
}